// Round 7
// baseline (292.213 us; speedup 1.0000x reference)
//
#include <hip/hip_runtime.h>
#include <hip/hip_bf16.h>

// TTN Conv: out[n,p,o,site] = sum_{c,i,j,k,l} a_i b_j c_k d_l * W[c,p,site,ijkl,o] + bias
// Per site: GEMM D[n=128][po=48] = sum_{k=768} A[n][k] * W[k][po], bf16 16x16x32 MFMA.
//
// R7: barrier-free phase-1. R4-R6 showed the LDS-staged K-loop stuck at ~81us
// (5x its memory floor) with ALL pipes idle -- structural: cross-wave W sharing
// forces a barrier per chunk, lock-stepping 961 blocks. Fix:
//   Phase 0: W [c,p,site][m][o] fp32 -> W' [c,p,site][o][m] bf16 (pure stream,
//            coalesced both sides, no LDS). 142MB R + 71MB W.
//   Phase 1: NO LDS, NO barriers. Lane (row,quad) loads its B-frag directly:
//            16 contiguous bytes of W' = one global_load_dwordx4 covering full
//            64B lines. Register double-buffer one chunk ahead. A-frags built
//            in regs from x factors (proven R4-R6 math, absmax 4.0).
//   Phase 2: tiled transpose ws(961x6144) -> out + bias (proven R2-R6).
//
// harness note: dur_us includes ~154us of 0xAA-poison fills (540MB d_ws) +
// restore; controllable part = phase0+phase1+phase2.

typedef __attribute__((ext_vector_type(8))) short short8;
typedef __attribute__((ext_vector_type(4))) float floatx4;

#define WS_ELEMS (961u * 6144u)                    // 23.6 MB fp32 ws
#define WP_OFFSET (32u * 1024u * 1024u)            // W' region at d_ws + 32MB
#define WP_BYTES ((size_t)23064u * 3072u)          // 3*8*961 units x 1536 shorts

static __device__ __forceinline__ unsigned pkbf(float lo, float hi) {
  __hip_bfloat162 h = __float22bfloat162_rn(make_float2(lo, hi));
  union { __hip_bfloat162 h; unsigned u; } v;
  v.h = h;
  return v.u;   // lo in [15:0], hi in [31:16]
}

// ---------- phase 0: W[cps][m][o] fp32 -> W'[cps][o][m] bf16 ----------
// thread = (cps, q): reads m-pair (2q,2q+1) x 6 o = 12 contiguous floats
// (3 float4, coalesced); writes 6 packed dwords, lanes contiguous per o-row.
__global__ __launch_bounds__(256)
void ttn_wprep(const float* __restrict__ tensors, unsigned* __restrict__ wp) {
  const int idx = blockIdx.x * 256 + threadIdx.x;   // 23064*128 exactly
  const int cps = idx >> 7, q = idx & 127;
  const float* src = tensors + (size_t)cps * 1536 + q * 12;
  const float4 v0 = *(const float4*)src;
  const float4 v1 = *(const float4*)(src + 4);
  const float4 v2 = *(const float4*)(src + 8);
  const float vv[12] = {v0.x, v0.y, v0.z, v0.w, v1.x, v1.y,
                        v1.z, v1.w, v2.x, v2.y, v2.z, v2.w};
  unsigned* dst = wp + (size_t)cps * 768 + q;       // dword view: [cps][o][128]
#pragma unroll
  for (int o = 0; o < 6; ++o)
    dst[o * 128] = pkbf(vv[o], vv[o + 6]);          // m=2q -> lo, m=2q+1 -> hi
}

// ---------- phase 1: barrier-free MFMA GEMM ----------
__global__ __launch_bounds__(256, 3)
void ttn_gemm(const float* __restrict__ x,
              const unsigned short* __restrict__ wp,
              float* __restrict__ ws) {
  const int site = blockIdx.x;
  const int xx = site / 31, yy = site - xx * 31;
  const int t = threadIdx.x, lane = t & 63, wave = t >> 6;
  const int row = lane & 15, quad = lane >> 4;

  // per-nt W' short-offset base: (p*961+site)*1536 + o*256 + quad*8
  int baseo[3];
#pragma unroll
  for (int nt = 0; nt < 3; ++nt) {
    const int po = nt * 16 + row;
    const int p = po / 6, o = po - p * 6;
    baseo[nt] = (p * 961 + site) * 1536 + o * 256 + quad * 8;
  }
  const size_t cstride = (size_t)8 * 961 * 1536;    // shorts per c

  floatx4 acc[2][3];
#pragma unroll
  for (int i0 = 0; i0 < 2; ++i0)
#pragma unroll
    for (int j0 = 0; j0 < 3; ++j0)
      acc[i0][j0] = (floatx4){0.f, 0.f, 0.f, 0.f};

  float a4[2][4], b2[2][2], cd8[2][8];
  short8 wbuf[2][6];

  auto loadChunk = [&](int ch, int buf) {
    const unsigned short* base = wp + (size_t)(ch >> 2) * cstride + (ch & 3) * 64;
#pragma unroll
    for (int nt = 0; nt < 3; ++nt)
#pragma unroll
      for (int ks = 0; ks < 2; ++ks)
        wbuf[buf][nt * 2 + ks] = *(const short8*)(base + baseo[nt] + ks * 32);
  };
  auto loadFactors = [&](int c) {
    const int qh = quad >> 1, ql = quad & 1;
#pragma unroll
    for (int mt = 0; mt < 2; ++mt) {
      const int n = wave * 32 + mt * 16 + row;
      const float* xb = x + ((size_t)n * 3 + c) * 4096 + xx * 32 + yy;
      float2 rAC[4], rBD[4];
#pragma unroll
      for (int i = 0; i < 4; ++i) {
        rAC[i] = *(const float2*)(xb + i * 1024);        // (a_i, c_i)
        rBD[i] = *(const float2*)(xb + i * 1024 + 32);   // (b_i, d_i)
      }
#pragma unroll
      for (int i = 0; i < 4; ++i) a4[mt][i] = rAC[i].x;
      b2[mt][0] = qh ? rBD[1].x : rBD[0].x;              // b_j, ks=0
      b2[mt][1] = qh ? rBD[3].x : rBD[2].x;              // b_j, ks=1
      const float cq0 = ql ? rAC[2].y : rAC[0].y;        // c_k
      const float cq1 = ql ? rAC[3].y : rAC[1].y;
#pragma unroll
      for (int j = 0; j < 8; ++j)
        cd8[mt][j] = (j < 4 ? cq0 : cq1) * rBD[j & 3].y; // c_k * d_l
    }
  };

  loadFactors(0);
  loadChunk(0, 0);

#pragma unroll
  for (int ch = 0; ch < 12; ++ch) {
    const int cur = ch & 1;
    if (ch == 4 || ch == 8) loadFactors(ch >> 2);   // L2-hot x, short stall ok
    if (ch < 11) loadChunk(ch + 1, cur ^ 1);        // stays in flight over compute
    const int mb = ch & 3;
#pragma unroll
    for (int ks = 0; ks < 2; ++ks)
#pragma unroll
      for (int mt = 0; mt < 2; ++mt) {
        const float ab = a4[mt][mb] * b2[mt][ks];
        union { unsigned u[4]; short8 s8; } af;
#pragma unroll
        for (int jj = 0; jj < 4; ++jj)
          af.u[jj] = pkbf(ab * cd8[mt][2 * jj], ab * cd8[mt][2 * jj + 1]);
#pragma unroll
        for (int nt = 0; nt < 3; ++nt)
          acc[mt][nt] = __builtin_amdgcn_mfma_f32_16x16x32_bf16(
              af.s8, wbuf[cur][nt * 2 + ks], acc[mt][nt], 0, 0, 0);
      }
  }

  // ws[site][n*48+po]: each store instr covers 4 full 64B lines
#pragma unroll
  for (int mt = 0; mt < 2; ++mt)
#pragma unroll
    for (int r = 0; r < 4; ++r) {
      const int n = wave * 32 + mt * 16 + quad * 4 + r;
#pragma unroll
      for (int nt = 0; nt < 3; ++nt)
        ws[(size_t)site * 6144 + n * 48 + nt * 16 + row] = acc[mt][nt][r];
    }
}

// ---------- phase 2: out[f*961+site] = ws[site*6144+f] + bias ----------
__global__ __launch_bounds__(256, 8)
void ttn_transpose_bias(const float* __restrict__ ws,
                        const float* __restrict__ bias,
                        float* __restrict__ out) {
  __shared__ float tile[32][33];
  const int f0 = blockIdx.x * 32;
  const int s0 = blockIdx.y * 32;
  const int tx = threadIdx.x, ty = threadIdx.y;

#pragma unroll
  for (int rr = 0; rr < 4; ++rr) {
    const int srow = ty + rr * 8;
    const int site = s0 + srow;
    if (site < 961)
      tile[srow][tx] = ws[(size_t)site * 6144 + f0 + tx];
  }
  __syncthreads();

#pragma unroll
  for (int rr = 0; rr < 4; ++rr) {
    const int fy = ty + rr * 8;
    const int f = f0 + fy;
    const int site = s0 + tx;
    if (site < 961) {
      const int po = f % 48;
      const int p = po / 6, o = po - p * 6;
      out[(size_t)f * 961 + site] = tile[tx][fy] + bias[(p * 961 + site) * 6 + o];
    }
  }
}

// ---------- fallback (ws too small): direct-store LDS kernel (R5-proven) ----------
#define SW_COLS 136
__global__ __launch_bounds__(256, 4)
void ttn_conv_direct(const float* __restrict__ x,
                     const float* __restrict__ tensors,
                     const float* __restrict__ bias,
                     float* __restrict__ dst) {
  __shared__ __align__(16) unsigned short sW[2][48 * SW_COLS];
  const int site = blockIdx.x;
  const int xx = site / 31, yy = site - xx * 31;
  const int t = threadIdx.x, lane = t & 63, wave = t >> 6;
  const int row = lane & 15, quad = lane >> 4;
  const int p_st = t >> 5, q_st = t & 31;

  floatx4 acc[2][3];
#pragma unroll
  for (int i0 = 0; i0 < 2; ++i0)
#pragma unroll
    for (int j0 = 0; j0 < 3; ++j0)
      acc[i0][j0] = (floatx4){0.f, 0.f, 0.f, 0.f};
  float a4[2][4], b2[2][2], cd8[2][8];
  float2 rAC[2][4], rBD[2][4];
  float4 wv[6];

  auto loadPair = [&](int s) {
    const float* base = tensors + ((size_t)(((s >> 1) * 8 + p_st) * 961 + site)) * 1536;
#pragma unroll
    for (int h = 0; h < 2; ++h) {
      const float* src = base + (size_t)((2 * (s & 1) + h) * 64 + 2 * q_st) * 6;
      wv[h * 3 + 0] = *(const float4*)src;
      wv[h * 3 + 1] = *(const float4*)(src + 4);
      wv[h * 3 + 2] = *(const float4*)(src + 8);
    }
  };
  auto storePair = [&](int buf) {
#pragma unroll
    for (int h = 0; h < 2; ++h) {
      const float4 w0 = wv[h * 3], w1 = wv[h * 3 + 1], w2 = wv[h * 3 + 2];
      const float vv[12] = {w0.x, w0.y, w0.z, w0.w, w1.x, w1.y,
                            w1.z, w1.w, w2.x, w2.y, w2.z, w2.w};
#pragma unroll
      for (int o = 0; o < 6; ++o)
        *(unsigned*)&sW[buf][(p_st * 6 + o) * SW_COLS + h * 64 + 2 * q_st] =
            pkbf(vv[o], vv[o + 6]);
    }
  };
  auto loadRaw = [&](int c) {
#pragma unroll
    for (int mt = 0; mt < 2; ++mt) {
      const int n = wave * 32 + mt * 16 + row;
      const float* xb = x + ((size_t)n * 3 + c) * 4096 + xx * 32 + yy;
#pragma unroll
      for (int i = 0; i < 4; ++i) {
        rAC[mt][i] = *(const float2*)(xb + i * 1024);
        rBD[mt][i] = *(const float2*)(xb + i * 1024 + 32);
      }
    }
  };
  auto cvtFactors = [&]() {
    const int qh = quad >> 1, ql = quad & 1;
#pragma unroll
    for (int mt = 0; mt < 2; ++mt) {
#pragma unroll
      for (int i = 0; i < 4; ++i) a4[mt][i] = rAC[mt][i].x;
      b2[mt][0] = qh ? rBD[mt][1].x : rBD[mt][0].x;
      b2[mt][1] = qh ? rBD[mt][3].x : rBD[mt][2].x;
      const float cq0 = ql ? rAC[mt][2].y : rAC[mt][0].y;
      const float cq1 = ql ? rAC[mt][3].y : rAC[mt][1].y;
#pragma unroll
      for (int j = 0; j < 8; ++j)
        cd8[mt][j] = (j < 4 ? cq0 : cq1) * rBD[mt][j & 3].y;
    }
  };

  loadPair(0); loadRaw(0); cvtFactors(); storePair(0); loadPair(1);
  __syncthreads();
#pragma unroll
  for (int s = 0; s < 6; ++s) {
    const int bp = s & 1;
    if (s <= 4) storePair(1 - bp);
    if (s <= 3) loadPair(s + 2);
    if (s == 1) loadRaw(1);
    if (s == 3) loadRaw(2);
    if (s == 2 || s == 4) cvtFactors();
#pragma unroll
    for (int ks = 0; ks < 4; ++ks) {
      const int mb = 2 * (s & 1) + (ks >> 1);
      short8 bfr[3];
#pragma unroll
      for (int nt = 0; nt < 3; ++nt)
        bfr[nt] = *(const short8*)&sW[bp][(nt * 16 + row) * SW_COLS + ks * 32 + quad * 8];
#pragma unroll
      for (int mt = 0; mt < 2; ++mt) {
        const float ab = a4[mt][mb] * b2[mt][ks & 1];
        union { unsigned u[4]; short8 s8; } af;
#pragma unroll
        for (int jj = 0; jj < 4; ++jj)
          af.u[jj] = pkbf(ab * cd8[mt][2 * jj], ab * cd8[mt][2 * jj + 1]);
#pragma unroll
        for (int nt = 0; nt < 3; ++nt)
          acc[mt][nt] = __builtin_amdgcn_mfma_f32_16x16x32_bf16(
              af.s8, bfr[nt], acc[mt][nt], 0, 0, 0);
      }
    }
    if (s < 5) __syncthreads();
  }
#pragma unroll
  for (int mt = 0; mt < 2; ++mt)
#pragma unroll
    for (int r = 0; r < 4; ++r) {
      const int n = wave * 32 + mt * 16 + quad * 4 + r;
#pragma unroll
      for (int nt = 0; nt < 3; ++nt) {
        const int po = nt * 16 + row;
        const int p = po / 6, o = po - p * 6;
        dst[(size_t)(n * 48 + po) * 961 + site] =
            acc[mt][nt][r] + bias[(p * 961 + site) * 6 + o];
      }
    }
}

extern "C" void kernel_launch(void* const* d_in, const int* in_sizes, int n_in,
                              void* d_out, int out_size, void* d_ws, size_t ws_size,
                              hipStream_t stream) {
  const float* x       = (const float*)d_in[0];
  const float* tensors = (const float*)d_in[1];
  const float* bias    = (const float*)d_in[2];
  float* out           = (float*)d_out;

  const size_t need = (size_t)WP_OFFSET + WP_BYTES;
  if (d_ws != nullptr && ws_size >= need) {
    float* ws = (float*)d_ws;
    unsigned* wp = (unsigned*)((char*)d_ws + WP_OFFSET);
    hipLaunchKernelGGL(ttn_wprep, dim3(11532), dim3(256), 0, stream, tensors, wp);
    hipLaunchKernelGGL(ttn_gemm, dim3(961), dim3(256), 0, stream,
                       x, (const unsigned short*)wp, ws);
    hipLaunchKernelGGL(ttn_transpose_bias, dim3(192, 31), dim3(32, 8), 0, stream,
                       ws, bias, out);
  } else {
    hipLaunchKernelGGL(ttn_conv_direct, dim3(961), dim3(256), 0, stream,
                       x, tensors, bias, out);
  }
}